// Round 1
// baseline (118.871 us; speedup 1.0000x reference)
//
#include <hip/hip_runtime.h>

#define NBATCH 32
#define DIST 5.0f
#define EPSV 1e-6f
#define INV_SQRT_F 0.17677669529663687f   // 1/sqrt(32)
#define SC_STAGE2 1.72633492e-4f          // 32^{-5/2}

__device__ __forceinline__ float silu_f(float v) { return v / (1.0f + expf(-v)); }

__device__ __forceinline__ void lower_bounds(const int* __restrict__ batch, int N, int b, int* sseg) {
  int lo = 0, hi = N;
  while (lo < hi) { int m = (lo + hi) >> 1; if (batch[m] < b) lo = m + 1; else hi = m; }
  sseg[0] = lo;
  int lo2 = lo, hi2 = N;
  while (lo2 < hi2) { int m = (lo2 + hi2) >> 1; if (batch[m] < b + 1) lo2 = m + 1; else hi2 = m; }
  sseg[1] = lo2;
}

extern "C" __global__ __launch_bounds__(256)
void stage1_kernel(const float* __restrict__ pos,
                   const int*   __restrict__ batch,
                   const float* __restrict__ xfeat,
                   const float* __restrict__ bw,
                   const float* __restrict__ Wqd,
                   const float* __restrict__ Wk1,
                   const float* __restrict__ Wk2,
                   const float* __restrict__ Wv1,
                   const float* __restrict__ Wv2,
                   const float* __restrict__ Wdot,
                   const float* __restrict__ initd,
                   float* __restrict__ out_dummy,   // NB*2*32
                   float* __restrict__ ws_ee,       // N*16
                   float* __restrict__ ws_sc,       // N*2
                   int N)
{
  const int b   = blockIdx.x;
  const int tid = threadIdx.x;

  __shared__ int   sseg[2];
  __shared__ float s_bw[8];
  __shared__ float s_Wk1[8][8], s_Wv1[8][8];
  __shared__ float s_qrow[32], s_c[32];
  __shared__ float s_Mk[32][8];          // [f][h], includes 1/1024
  __shared__ float s_red[256];
  __shared__ float s_zmin, s_zmax;
  __shared__ float s_smax[2], s_denom[2];
  __shared__ float s_exh[256][16];       // ex[s]*hv[s][h]
  __shared__ float s_xs[256][32];
  __shared__ float s_Tpart[4][512];
  __shared__ float s_T[512];

  if (tid == 0) lower_bounds(batch, N, b, sseg);
  if (tid < 8)  s_bw[tid] = bw[tid];
  if (tid < 64) { s_Wk1[tid >> 3][tid & 7] = Wk1[tid]; s_Wv1[tid >> 3][tid & 7] = Wv1[tid]; }
  __syncthreads();
  const int s0 = sseg[0], s1 = sseg[1];
  const int cnt = s1 - s0;

  // ---- pass A: segment z min/max ----
  float zmn = INFINITY, zmx = -INFINITY;
  for (int i = s0 + tid; i < s1; i += 256) {
    float z = pos[3 * i + 2];
    zmn = fminf(zmn, z); zmx = fmaxf(zmx, z);
  }
  s_red[tid] = zmn; __syncthreads();
  for (int off = 128; off > 0; off >>= 1) { if (tid < off) s_red[tid] = fminf(s_red[tid], s_red[tid + off]); __syncthreads(); }
  if (tid == 0) s_zmin = s_red[0];
  __syncthreads();
  s_red[tid] = zmx; __syncthreads();
  for (int off = 128; off > 0; off >>= 1) { if (tid < off) s_red[tid] = fmaxf(s_red[tid], s_red[tid + off]); __syncthreads(); }
  if (tid == 0) s_zmax = s_red[0];
  __syncthreads();

  // ---- per-block constants: q_row, c, Mk ----
  if (tid < 32) {
    float a = 0.f;
    for (int f = 0; f < 32; f++) a += initd[f] * Wqd[f * 32 + tid];
    s_qrow[tid] = a * INV_SQRT_F;
  }
  __syncthreads();
  if (tid < 32) {
    float a = 0.f;
    for (int f = 0; f < 32; f++) a += s_qrow[f] * Wdot[f * 32 + tid];
    s_c[tid] = a;
  }
  __syncthreads();
  {
    int f = tid >> 3, h = tid & 7;
    const float* w = &Wk2[h * 1024 + f * 32];
    float a = 0.f;
    for (int g = 0; g < 32; g++) a += w[g] * s_c[g];
    s_Mk[f][h] = a * (1.0f / 1024.0f);
  }
  __syncthreads();

  // ---- pass B: edge_emb (stored), scores (stored), running max ----
  const float zmin = s_zmin, zmax = s_zmax;
  float mloc0 = -INFINITY, mloc1 = -INFINITY;
  for (int i = s0 + tid; i < s1; i += 256) {
    float z = pos[3 * i + 2];
    float len0 = z - zmin + DIST;
    float len1 = zmax + DIST - z;
    float xv[32];
    const float4* xp = (const float4*)&xfeat[(size_t)i * 32];
    #pragma unroll
    for (int q = 0; q < 8; q++) { float4 t = xp[q]; xv[4*q] = t.x; xv[4*q+1] = t.y; xv[4*q+2] = t.z; xv[4*q+3] = t.w; }
    float u[8] = {0,0,0,0,0,0,0,0};
    #pragma unroll
    for (int f = 0; f < 32; f++) {
      float xf = xv[f];
      #pragma unroll
      for (int h = 0; h < 8; h++) u[h] += xf * s_Mk[f][h];
    }
    float4* eeo = (float4*)&ws_ee[(size_t)i * 16];
    float sc[2];
    #pragma unroll
    for (int s = 0; s < 2; s++) {
      float L = s ? len1 : len0;
      float inv = 1.0f / (L + EPSV);
      float ee[8];
      #pragma unroll
      for (int j = 0; j < 8; j++) ee[j] = sinf(s_bw[j] * L) * inv;
      eeo[2*s]   = make_float4(ee[0], ee[1], ee[2], ee[3]);
      eeo[2*s+1] = make_float4(ee[4], ee[5], ee[6], ee[7]);
      float acc = 0.f;
      #pragma unroll
      for (int h = 0; h < 8; h++) {
        float a = 0.f;
        #pragma unroll
        for (int j = 0; j < 8; j++) a += ee[j] * s_Wk1[j][h];
        acc += silu_f(a) * u[h];
      }
      sc[s] = acc;
    }
    ws_sc[2 * (size_t)i]     = sc[0];
    ws_sc[2 * (size_t)i + 1] = sc[1];
    mloc0 = fmaxf(mloc0, sc[0]);
    mloc1 = fmaxf(mloc1, sc[1]);
  }
  s_red[tid] = mloc0; __syncthreads();
  for (int off = 128; off > 0; off >>= 1) { if (tid < off) s_red[tid] = fmaxf(s_red[tid], s_red[tid + off]); __syncthreads(); }
  if (tid == 0) s_smax[0] = s_red[0];
  __syncthreads();
  s_red[tid] = mloc1; __syncthreads();
  for (int off = 128; off > 0; off >>= 1) { if (tid < off) s_red[tid] = fmaxf(s_red[tid], s_red[tid + off]); __syncthreads(); }
  if (tid == 0) s_smax[1] = s_red[0];
  __syncthreads();

  // ---- pass C: exp, denom, T[s,h,f] accumulation (slot ownership) ----
  float Treg[8] = {0,0,0,0,0,0,0,0};
  float d0 = 0.f, d1 = 0.f;
  const int group = tid >> 6;    // 0..3 (one wave each)
  const int gt    = tid & 63;
  const int osh   = gt >> 2;     // 0..15  = s*8+h
  const int ofg   = gt & 3;      // f-block of 8
  const float sm0 = s_smax[0], sm1 = s_smax[1];
  for (int base = s0; base < s1; base += 256) {
    int i = base + tid;
    if (i < s1) {
      float ex0 = expf(ws_sc[2 * (size_t)i]     - sm0);
      float ex1 = expf(ws_sc[2 * (size_t)i + 1] - sm1);
      d0 += ex0; d1 += ex1;
      const float4* eei = (const float4*)&ws_ee[(size_t)i * 16];
      float ee[16];
      #pragma unroll
      for (int q = 0; q < 4; q++) { float4 t = eei[q]; ee[4*q] = t.x; ee[4*q+1] = t.y; ee[4*q+2] = t.z; ee[4*q+3] = t.w; }
      #pragma unroll
      for (int s = 0; s < 2; s++) {
        float exv = s ? ex1 : ex0;
        #pragma unroll
        for (int h = 0; h < 8; h++) {
          float a = 0.f;
          #pragma unroll
          for (int j = 0; j < 8; j++) a += ee[8*s + j] * s_Wv1[j][h];
          s_exh[tid][8*s + h] = exv * silu_f(a);
        }
      }
      const float4* xp = (const float4*)&xfeat[(size_t)i * 32];
      float4* xso = (float4*)s_xs[tid];
      #pragma unroll
      for (int q = 0; q < 8; q++) xso[q] = xp[q];
    } else {
      #pragma unroll
      for (int h = 0; h < 16; h++) s_exh[tid][h] = 0.f;
      float4* xso = (float4*)s_xs[tid];
      #pragma unroll
      for (int q = 0; q < 8; q++) xso[q] = make_float4(0.f, 0.f, 0.f, 0.f);
    }
    __syncthreads();
    const int cbeg = group * 64;
    for (int c = cbeg; c < cbeg + 64; c++) {
      float eh = s_exh[c][osh];
      const float* xr = &s_xs[c][ofg * 8];
      #pragma unroll
      for (int k = 0; k < 8; k++) Treg[k] += eh * xr[k];
    }
    __syncthreads();
  }
  #pragma unroll
  for (int k = 0; k < 8; k++) s_Tpart[group][osh * 32 + ofg * 8 + k] = Treg[k];
  __syncthreads();
  for (int idx = tid; idx < 512; idx += 256)
    s_T[idx] = s_Tpart[0][idx] + s_Tpart[1][idx] + s_Tpart[2][idx] + s_Tpart[3][idx];
  // denom reductions (syncs below also fence s_T writes)
  s_red[tid] = d0; __syncthreads();
  for (int off = 128; off > 0; off >>= 1) { if (tid < off) s_red[tid] += s_red[tid + off]; __syncthreads(); }
  if (tid == 0) s_denom[0] = s_red[0];
  __syncthreads();
  s_red[tid] = d1; __syncthreads();
  for (int off = 128; off > 0; off >>= 1) { if (tid < off) s_red[tid] += s_red[tid + off]; __syncthreads(); }
  if (tid == 0) s_denom[1] = s_red[0];
  __syncthreads();

  // ---- agg and dummy_out ----
  if (tid < 64) {
    int s = tid >> 5, g = tid & 31;
    float acc = 0.f;
    #pragma unroll
    for (int h = 0; h < 8; h++) {
      const float* wv = &Wv2[h * 1024 + g];
      const float* Ts = &s_T[(8 * s + h) * 32];
      #pragma unroll
      for (int f = 0; f < 32; f++) acc += Ts[f] * wv[f * 32];
    }
    float agg = (cnt > 0) ? acc * INV_SQRT_F / s_denom[s] : 0.0f;
    out_dummy[b * 64 + s * 32 + g] = initd[g] + agg;
  }
}

extern "C" __global__ __launch_bounds__(256)
void stage2_kernel(const int*   __restrict__ batch,
                   const float* __restrict__ xfeat,
                   const float* __restrict__ Wqg,
                   const float* __restrict__ Wkg1,
                   const float* __restrict__ Wkg2,
                   const float* __restrict__ Wvg1,
                   const float* __restrict__ Wvg2,
                   const float* __restrict__ Wdot,
                   const float* __restrict__ dummy_out,
                   const float* __restrict__ ws_ee,
                   float* __restrict__ out_node,
                   int N, int KB)
{
  const int b   = blockIdx.x / KB;
  const int jb  = blockIdx.x % KB;
  const int tid = threadIdx.x;

  __shared__ int   sseg[2];
  __shared__ float s_WQD[32][32];
  __shared__ float s_Bkg[16][32];
  __shared__ float s_Bvg[16][32];
  __shared__ float s_G[32][16];         // [f][s*8+h], includes 32^{-5/2}
  __shared__ float s_Wkg1[8][8], s_Wvg1[8][8];
  __shared__ float s_dummy[2][32];

  if (tid == 0) lower_bounds(batch, N, b, sseg);
  if (tid < 64) { s_Wkg1[tid >> 3][tid & 7] = Wkg1[tid]; s_Wvg1[tid >> 3][tid & 7] = Wvg1[tid]; }
  if (tid < 64) s_dummy[tid >> 5][tid & 31] = dummy_out[b * 64 + tid];
  for (int idx = tid; idx < 1024; idx += 256) {
    int f = idx >> 5, g = idx & 31;
    float a = 0.f;
    for (int k = 0; k < 32; k++) a += Wqg[f * 32 + k] * Wdot[k * 32 + g];
    s_WQD[f][g] = a;
  }
  __syncthreads();
  for (int idx = tid; idx < 512; idx += 256) {
    int sh = idx >> 5, g = idx & 31;
    int s = sh >> 3, h = sh & 7;
    const float* wk = &Wkg2[h * 1024 + g];
    const float* wv = &Wvg2[h * 1024 + g];
    float a = 0.f, v = 0.f;
    #pragma unroll
    for (int f = 0; f < 32; f++) { float d = s_dummy[s][f]; a += d * wk[f * 32]; v += d * wv[f * 32]; }
    s_Bkg[sh][g] = a; s_Bvg[sh][g] = v;
  }
  __syncthreads();
  for (int idx = tid; idx < 512; idx += 256) {
    int f = idx >> 4, sh = idx & 15;
    float a = 0.f;
    #pragma unroll
    for (int g = 0; g < 32; g++) a += s_WQD[f][g] * s_Bkg[sh][g];
    s_G[f][sh] = a * SC_STAGE2;
  }
  __syncthreads();

  const int s0 = sseg[0], s1 = sseg[1];
  const int cnt = s1 - s0;
  const int per = (cnt + KB - 1) / KB;
  const int lo = s0 + jb * per;
  const int hi = min(lo + per, s1);

  for (int i = lo + tid; i < hi; i += 256) {
    float ee[16];
    const float4* eei = (const float4*)&ws_ee[(size_t)i * 16];
    #pragma unroll
    for (int q = 0; q < 4; q++) { float4 t = eei[q]; ee[4*q] = t.x; ee[4*q+1] = t.y; ee[4*q+2] = t.z; ee[4*q+3] = t.w; }
    float hkg[16], hvg[16];
    #pragma unroll
    for (int s = 0; s < 2; s++) {
      #pragma unroll
      for (int h = 0; h < 8; h++) {
        float a = 0.f, v = 0.f;
        #pragma unroll
        for (int j = 0; j < 8; j++) { a += ee[8*s + j] * s_Wkg1[j][h]; v += ee[8*s + j] * s_Wvg1[j][h]; }
        hkg[8*s + h] = silu_f(a); hvg[8*s + h] = silu_f(v);
      }
    }
    float xv[32];
    const float4* xp = (const float4*)&xfeat[(size_t)i * 32];
    #pragma unroll
    for (int q = 0; q < 8; q++) { float4 t = xp[q]; xv[4*q] = t.x; xv[4*q+1] = t.y; xv[4*q+2] = t.z; xv[4*q+3] = t.w; }
    float ev[16] = {0,0,0,0,0,0,0,0,0,0,0,0,0,0,0,0};
    #pragma unroll
    for (int f = 0; f < 32; f++) {
      float xf = xv[f];
      #pragma unroll
      for (int sh = 0; sh < 16; sh++) ev[sh] += xf * s_G[f][sh];
    }
    float sc0 = 0.f, sc1 = 0.f;
    #pragma unroll
    for (int h = 0; h < 8; h++) { sc0 += hkg[h] * ev[h]; sc1 += hkg[8 + h] * ev[8 + h]; }
    float m = fmaxf(sc0, sc1);
    float a0 = expf(sc0 - m), a1 = expf(sc1 - m);
    float invd = 1.0f / (a0 + a1);
    float w0 = a0 * invd * INV_SQRT_F, w1 = a1 * invd * INV_SQRT_F;
    float ov[32];
    #pragma unroll
    for (int g = 0; g < 32; g++) ov[g] = xv[g];
    #pragma unroll
    for (int sh = 0; sh < 16; sh++) {
      float w = (sh < 8 ? w0 : w1) * hvg[sh];
      #pragma unroll
      for (int g = 0; g < 32; g++) ov[g] += w * s_Bvg[sh][g];
    }
    float4* op = (float4*)&out_node[(size_t)i * 32];
    #pragma unroll
    for (int q = 0; q < 8; q++) op[q] = make_float4(ov[4*q], ov[4*q+1], ov[4*q+2], ov[4*q+3]);
  }
}

extern "C" void kernel_launch(void* const* d_in, const int* in_sizes, int n_in,
                              void* d_out, int out_size, void* d_ws, size_t ws_size,
                              hipStream_t stream)
{
  const float* pos   = (const float*)d_in[0];
  const int*   batch = (const int*)d_in[1];
  const float* xf    = (const float*)d_in[2];
  const float* bw    = (const float*)d_in[3];
  const float* Wqd   = (const float*)d_in[4];
  const float* Wk1   = (const float*)d_in[5];
  const float* Wk2   = (const float*)d_in[6];
  const float* Wv1   = (const float*)d_in[7];
  const float* Wv2   = (const float*)d_in[8];
  const float* Wqg   = (const float*)d_in[9];
  const float* Wkg1  = (const float*)d_in[10];
  const float* Wkg2  = (const float*)d_in[11];
  const float* Wvg1  = (const float*)d_in[12];
  const float* Wvg2  = (const float*)d_in[13];
  const float* Wdot  = (const float*)d_in[14];
  const float* initd = (const float*)d_in[15];
  const int N = in_sizes[1];

  float* out       = (float*)d_out;
  float* out_node  = out;
  float* out_dummy = out + (size_t)N * 32;

  float* ws    = (float*)d_ws;
  float* ws_ee = ws;                      // N*16 floats
  float* ws_sc = ws + (size_t)16 * N;     // N*2 floats

  stage1_kernel<<<NBATCH, 256, 0, stream>>>(pos, batch, xf, bw, Wqd, Wk1, Wk2, Wv1, Wv2,
                                            Wdot, initd, out_dummy, ws_ee, ws_sc, N);
  const int KB = 8;
  stage2_kernel<<<NBATCH * KB, 256, 0, stream>>>(batch, xf, Wqg, Wkg1, Wkg2, Wvg1, Wvg2,
                                                 Wdot, out_dummy, ws_ee, out_node, N, KB);
}

// Round 2
// 97.690 us; speedup vs baseline: 1.2168x; 1.2168x over previous
//
#include <hip/hip_runtime.h>

#define NBATCH 32
#define DIST 5.0f
#define EPSV 1e-6f
#define INV_SQRT_F 0.17677669529663687f   // 1/sqrt(32)
#define SC_STAGE2 1.72633492e-4f          // 32^{-5/2}
#define KBS1 8    // slices per batch, stage-1 fused kernel -> 256 blocks
#define KBS2 16   // slices per batch, stage-2 kernel       -> 512 blocks

__device__ __forceinline__ float silu_f(float v) { return v / (1.0f + expf(-v)); }

// monotonic float <-> uint mapping for atomic min/max on float values
__device__ __forceinline__ unsigned f2key(float f) {
  unsigned u = __float_as_uint(f);
  return (u & 0x80000000u) ? ~u : (u | 0x80000000u);
}
__device__ __forceinline__ float key2f(unsigned k) {
  return (k & 0x80000000u) ? __uint_as_float(k ^ 0x80000000u) : __uint_as_float(~k);
}

__device__ __forceinline__ void lower_bounds(const int* __restrict__ batch, int N, int b, int* sseg) {
  int lo = 0, hi = N;
  while (lo < hi) { int m = (lo + hi) >> 1; if (batch[m] < b) lo = m + 1; else hi = m; }
  sseg[0] = lo;
  int lo2 = lo, hi2 = N;
  while (lo2 < hi2) { int m = (lo2 + hi2) >> 1; if (batch[m] < b + 1) lo2 = m + 1; else hi2 = m; }
  sseg[1] = lo2;
}

// ---------------- kernel A: per-batch z min/max via atomic keys ----------------
extern "C" __global__ __launch_bounds__(256)
void zminmax_kernel(const float* __restrict__ pos, const int* __restrict__ batch,
                    unsigned* __restrict__ zminkey, unsigned* __restrict__ zmaxkey, int N)
{
  __shared__ unsigned smin[NBATCH], smax[NBATCH];
  const int tid = threadIdx.x;
  if (tid < NBATCH) { smin[tid] = 0xFFFFFFFFu; smax[tid] = 0u; }
  __syncthreads();
  int i = blockIdx.x * 256 + tid;
  if (i < N) {
    unsigned k = f2key(pos[3 * (size_t)i + 2]);
    int b = batch[i];
    atomicMin(&smin[b], k);
    atomicMax(&smax[b], k);
  }
  __syncthreads();
  if (tid < NBATCH) {
    if (smin[tid] != 0xFFFFFFFFu) atomicMin(&zminkey[tid], smin[tid]);
    if (smax[tid] != 0u)          atomicMax(&zmaxkey[tid], smax[tid]);
  }
}

// ---------------- kernel B: fused per-node stage-1 (ee, scores, exp, T, denom) ----------------
extern "C" __global__ __launch_bounds__(256)
void fused1_kernel(const float* __restrict__ pos,
                   const int*   __restrict__ batch,
                   const float* __restrict__ xfeat,
                   const float* __restrict__ bw,
                   const float* __restrict__ Wqd,
                   const float* __restrict__ Wk1,
                   const float* __restrict__ Wk2,
                   const float* __restrict__ Wv1,
                   const float* __restrict__ Wdot,
                   const float* __restrict__ initd,
                   const unsigned* __restrict__ zminkey,
                   const unsigned* __restrict__ zmaxkey,
                   float* __restrict__ Tacc,     // NB * 512
                   float* __restrict__ den,      // NB * 2
                   float* __restrict__ ws_ee,    // N * 16
                   int N)
{
  const int b   = blockIdx.x / KBS1;
  const int jb  = blockIdx.x % KBS1;
  const int tid = threadIdx.x;

  __shared__ int   sseg[2];
  __shared__ float s_bw[8];
  __shared__ float s_Wk1[8][8], s_Wv1[8][8];
  __shared__ float s_qrow[32], s_c[32];
  __shared__ float s_Mk[32][8];          // [f][h], includes 1/1024
  __shared__ float s_exh[256][16];       // ex[s]*hv[s][h]
  __shared__ float s_xs[256][32];
  __shared__ float s_Tpart[4][512];
  __shared__ float s_red[256];

  if (tid == 0) lower_bounds(batch, N, b, sseg);
  if (tid < 8)  s_bw[tid] = bw[tid];
  if (tid < 64) { s_Wk1[tid >> 3][tid & 7] = Wk1[tid]; s_Wv1[tid >> 3][tid & 7] = Wv1[tid]; }
  if (tid < 32) {
    float a = 0.f;
    for (int f = 0; f < 32; f++) a += initd[f] * Wqd[f * 32 + tid];
    s_qrow[tid] = a * INV_SQRT_F;
  }
  __syncthreads();
  if (tid < 32) {
    float a = 0.f;
    for (int f = 0; f < 32; f++) a += s_qrow[f] * Wdot[f * 32 + tid];
    s_c[tid] = a;
  }
  __syncthreads();
  {
    int f = tid >> 3, h = tid & 7;
    const float* w = &Wk2[h * 1024 + f * 32];
    float a = 0.f;
    for (int g = 0; g < 32; g++) a += w[g] * s_c[g];
    s_Mk[f][h] = a * (1.0f / 1024.0f);
  }
  const float zmin = key2f(zminkey[b]);
  const float zmax = key2f(zmaxkey[b]);
  __syncthreads();

  const int s0 = sseg[0], s1 = sseg[1];
  const int cnt = s1 - s0;
  const int per = (cnt + KBS1 - 1) / KBS1;
  const int lo  = s0 + jb * per;
  const int hi  = min(lo + per, s1);

  float Treg[8] = {0,0,0,0,0,0,0,0};
  float d0 = 0.f, d1 = 0.f;
  const int group = tid >> 6;    // 0..3
  const int gt    = tid & 63;
  const int osh   = gt >> 2;     // 0..15 = s*8+h
  const int ofg   = gt & 3;      // f-block of 8

  for (int base = lo; base < hi; base += 256) {
    int i = base + tid;
    if (i < hi) {
      float z = pos[3 * (size_t)i + 2];
      float len0 = z - zmin + DIST;
      float len1 = zmax + DIST - z;
      float xv[32];
      const float4* xp = (const float4*)&xfeat[(size_t)i * 32];
      float4* xso = (float4*)s_xs[tid];
      #pragma unroll
      for (int q = 0; q < 8; q++) {
        float4 t = xp[q];
        xso[q] = t;
        xv[4*q] = t.x; xv[4*q+1] = t.y; xv[4*q+2] = t.z; xv[4*q+3] = t.w;
      }
      float u[8] = {0,0,0,0,0,0,0,0};
      #pragma unroll
      for (int f = 0; f < 32; f++) {
        float xf = xv[f];
        #pragma unroll
        for (int h = 0; h < 8; h++) u[h] += xf * s_Mk[f][h];
      }
      float4* eeo = (float4*)&ws_ee[(size_t)i * 16];
      #pragma unroll
      for (int s = 0; s < 2; s++) {
        float L = s ? len1 : len0;
        float inv = 1.0f / (L + EPSV);
        float ee[8];
        #pragma unroll
        for (int j = 0; j < 8; j++) ee[j] = sinf(s_bw[j] * L) * inv;
        eeo[2*s]   = make_float4(ee[0], ee[1], ee[2], ee[3]);
        eeo[2*s+1] = make_float4(ee[4], ee[5], ee[6], ee[7]);
        float sc = 0.f;
        #pragma unroll
        for (int h = 0; h < 8; h++) {
          float a = 0.f;
          #pragma unroll
          for (int j = 0; j < 8; j++) a += ee[j] * s_Wk1[j][h];
          sc += silu_f(a) * u[h];
        }
        // softmax without max-subtraction (exact: ratio-invariant; clamp = overflow guard)
        float ex = expf(fminf(fmaxf(sc, -60.f), 60.f));
        if (s) d1 += ex; else d0 += ex;
        #pragma unroll
        for (int h = 0; h < 8; h++) {
          float v = 0.f;
          #pragma unroll
          for (int j = 0; j < 8; j++) v += ee[j] * s_Wv1[j][h];
          s_exh[tid][8*s + h] = ex * silu_f(v);
        }
      }
    } else {
      #pragma unroll
      for (int h = 0; h < 16; h++) s_exh[tid][h] = 0.f;
      float4* xso = (float4*)s_xs[tid];
      #pragma unroll
      for (int q = 0; q < 8; q++) xso[q] = make_float4(0.f, 0.f, 0.f, 0.f);
    }
    __syncthreads();
    const int cbeg = group * 64;
    for (int c = cbeg; c < cbeg + 64; c++) {
      float eh = s_exh[c][osh];
      const float* xr = &s_xs[c][ofg * 8];
      #pragma unroll
      for (int k = 0; k < 8; k++) Treg[k] += eh * xr[k];
    }
    __syncthreads();
  }

  #pragma unroll
  for (int k = 0; k < 8; k++) s_Tpart[group][osh * 32 + ofg * 8 + k] = Treg[k];
  __syncthreads();
  for (int idx = tid; idx < 512; idx += 256) {
    float v = s_Tpart[0][idx] + s_Tpart[1][idx] + s_Tpart[2][idx] + s_Tpart[3][idx];
    atomicAdd(&Tacc[b * 512 + idx], v);
  }
  s_red[tid] = d0; __syncthreads();
  for (int off = 128; off > 0; off >>= 1) { if (tid < off) s_red[tid] += s_red[tid + off]; __syncthreads(); }
  if (tid == 0) atomicAdd(&den[b * 2 + 0], s_red[0]);
  __syncthreads();
  s_red[tid] = d1; __syncthreads();
  for (int off = 128; off > 0; off >>= 1) { if (tid < off) s_red[tid] += s_red[tid + off]; __syncthreads(); }
  if (tid == 0) atomicAdd(&den[b * 2 + 1], s_red[0]);
}

// ---------------- kernel C: stage-2 (dummy epilogue fused into prologue) ----------------
extern "C" __global__ __launch_bounds__(256)
void stage2_kernel(const int*   __restrict__ batch,
                   const float* __restrict__ xfeat,
                   const float* __restrict__ Wqg,
                   const float* __restrict__ Wkg1,
                   const float* __restrict__ Wkg2,
                   const float* __restrict__ Wvg1,
                   const float* __restrict__ Wvg2,
                   const float* __restrict__ Wdot,
                   const float* __restrict__ Wv2,
                   const float* __restrict__ initd,
                   const float* __restrict__ Tacc,
                   const float* __restrict__ den,
                   const float* __restrict__ ws_ee,
                   float* __restrict__ out_node,
                   float* __restrict__ out_dummy,
                   int N)
{
  const int b   = blockIdx.x / KBS2;
  const int jb  = blockIdx.x % KBS2;
  const int tid = threadIdx.x;

  __shared__ int   sseg[2];
  __shared__ float s_WQD[32][32];
  __shared__ float s_Bkg[16][32];
  __shared__ float s_Bvg[16][32];
  __shared__ float s_G[32][16];         // [f][s*8+h], includes 32^{-5/2}
  __shared__ float s_Wkg1[8][8], s_Wvg1[8][8];
  __shared__ float s_dummy[2][32];

  if (tid == 0) lower_bounds(batch, N, b, sseg);
  if (tid < 64) { s_Wkg1[tid >> 3][tid & 7] = Wkg1[tid]; s_Wvg1[tid >> 3][tid & 7] = Wvg1[tid]; }
  if (tid < 64) {
    // dummy_out[b,s,:] = initd + invsF/den * sum_h sum_f T[s*8+h][f] * Wv2[h, f*32+g]
    int s = tid >> 5, g = tid & 31;
    float acc = 0.f;
    #pragma unroll
    for (int h = 0; h < 8; h++) {
      const float* wv = &Wv2[h * 1024 + g];
      const float* Ts = &Tacc[b * 512 + (8 * s + h) * 32];
      #pragma unroll
      for (int f = 0; f < 32; f++) acc += Ts[f] * wv[f * 32];
    }
    float dn = den[b * 2 + s];
    float dv = initd[g] + (dn > 0.f ? acc * INV_SQRT_F / dn : 0.f);
    s_dummy[s][g] = dv;
    if (jb == 0) out_dummy[b * 64 + s * 32 + g] = dv;
  }
  for (int idx = tid; idx < 1024; idx += 256) {
    int f = idx >> 5, g = idx & 31;
    float a = 0.f;
    for (int k = 0; k < 32; k++) a += Wqg[f * 32 + k] * Wdot[k * 32 + g];
    s_WQD[f][g] = a;
  }
  __syncthreads();
  for (int idx = tid; idx < 512; idx += 256) {
    int sh = idx >> 5, g = idx & 31;
    int s = sh >> 3, h = sh & 7;
    const float* wk = &Wkg2[h * 1024 + g];
    const float* wv = &Wvg2[h * 1024 + g];
    float a = 0.f, v = 0.f;
    #pragma unroll
    for (int f = 0; f < 32; f++) { float d = s_dummy[s][f]; a += d * wk[f * 32]; v += d * wv[f * 32]; }
    s_Bkg[sh][g] = a; s_Bvg[sh][g] = v;
  }
  __syncthreads();
  for (int idx = tid; idx < 512; idx += 256) {
    int f = idx >> 4, sh = idx & 15;
    float a = 0.f;
    #pragma unroll
    for (int g = 0; g < 32; g++) a += s_WQD[f][g] * s_Bkg[sh][g];
    s_G[f][sh] = a * SC_STAGE2;
  }
  __syncthreads();

  const int s0 = sseg[0], s1 = sseg[1];
  const int cnt = s1 - s0;
  const int per = (cnt + KBS2 - 1) / KBS2;
  const int lo = s0 + jb * per;
  const int hi = min(lo + per, s1);

  for (int i = lo + tid; i < hi; i += 256) {
    float ee[16];
    const float4* eei = (const float4*)&ws_ee[(size_t)i * 16];
    #pragma unroll
    for (int q = 0; q < 4; q++) { float4 t = eei[q]; ee[4*q] = t.x; ee[4*q+1] = t.y; ee[4*q+2] = t.z; ee[4*q+3] = t.w; }
    float hkg[16], hvg[16];
    #pragma unroll
    for (int s = 0; s < 2; s++) {
      #pragma unroll
      for (int h = 0; h < 8; h++) {
        float a = 0.f, v = 0.f;
        #pragma unroll
        for (int j = 0; j < 8; j++) { a += ee[8*s + j] * s_Wkg1[j][h]; v += ee[8*s + j] * s_Wvg1[j][h]; }
        hkg[8*s + h] = silu_f(a); hvg[8*s + h] = silu_f(v);
      }
    }
    float xv[32];
    const float4* xp = (const float4*)&xfeat[(size_t)i * 32];
    #pragma unroll
    for (int q = 0; q < 8; q++) { float4 t = xp[q]; xv[4*q] = t.x; xv[4*q+1] = t.y; xv[4*q+2] = t.z; xv[4*q+3] = t.w; }
    float ev[16] = {0,0,0,0,0,0,0,0,0,0,0,0,0,0,0,0};
    #pragma unroll
    for (int f = 0; f < 32; f++) {
      float xf = xv[f];
      #pragma unroll
      for (int sh = 0; sh < 16; sh++) ev[sh] += xf * s_G[f][sh];
    }
    float sc0 = 0.f, sc1 = 0.f;
    #pragma unroll
    for (int h = 0; h < 8; h++) { sc0 += hkg[h] * ev[h]; sc1 += hkg[8 + h] * ev[8 + h]; }
    float m = fmaxf(sc0, sc1);
    float a0 = expf(sc0 - m), a1 = expf(sc1 - m);
    float invd = 1.0f / (a0 + a1);
    float w0 = a0 * invd * INV_SQRT_F, w1 = a1 * invd * INV_SQRT_F;
    float ov[32];
    #pragma unroll
    for (int g = 0; g < 32; g++) ov[g] = xv[g];
    #pragma unroll
    for (int sh = 0; sh < 16; sh++) {
      float w = (sh < 8 ? w0 : w1) * hvg[sh];
      #pragma unroll
      for (int g = 0; g < 32; g++) ov[g] += w * s_Bvg[sh][g];
    }
    float4* op = (float4*)&out_node[(size_t)i * 32];
    #pragma unroll
    for (int q = 0; q < 8; q++) op[q] = make_float4(ov[4*q], ov[4*q+1], ov[4*q+2], ov[4*q+3]);
  }
}

extern "C" void kernel_launch(void* const* d_in, const int* in_sizes, int n_in,
                              void* d_out, int out_size, void* d_ws, size_t ws_size,
                              hipStream_t stream)
{
  const float* pos   = (const float*)d_in[0];
  const int*   batch = (const int*)d_in[1];
  const float* xf    = (const float*)d_in[2];
  const float* bw    = (const float*)d_in[3];
  const float* Wqd   = (const float*)d_in[4];
  const float* Wk1   = (const float*)d_in[5];
  const float* Wk2   = (const float*)d_in[6];
  const float* Wv1   = (const float*)d_in[7];
  const float* Wv2   = (const float*)d_in[8];
  const float* Wqg   = (const float*)d_in[9];
  const float* Wkg1  = (const float*)d_in[10];
  const float* Wkg2  = (const float*)d_in[11];
  const float* Wvg1  = (const float*)d_in[12];
  const float* Wvg2  = (const float*)d_in[13];
  const float* Wdot  = (const float*)d_in[14];
  const float* initd = (const float*)d_in[15];
  const int N = in_sizes[1];

  float* out       = (float*)d_out;
  float* out_node  = out;
  float* out_dummy = out + (size_t)N * 32;

  // workspace layout (float offsets)
  float*    ws        = (float*)d_ws;
  float*    ws_T      = ws;                           // 32*512 = 16384
  float*    ws_den    = ws + 16384;                   // 64
  unsigned* ws_zmaxk  = (unsigned*)(ws + 16448);      // 32 (init 0)
  unsigned* ws_zmink  = (unsigned*)(ws + 16480);      // 32 (init 0xFFFFFFFF)
  float*    ws_ee     = ws + 16512;                   // N*16

  // init: zero T+den+zmaxkey, 0xFF zminkey (graph-capturable memset nodes)
  hipMemsetAsync(ws_T, 0, (size_t)16480 * 4, stream);
  hipMemsetAsync(ws_zmink, 0xFF, (size_t)32 * 4, stream);

  zminmax_kernel<<<(N + 255) / 256, 256, 0, stream>>>(pos, batch, ws_zmink, ws_zmaxk, N);

  fused1_kernel<<<NBATCH * KBS1, 256, 0, stream>>>(pos, batch, xf, bw, Wqd, Wk1, Wk2, Wv1,
                                                   Wdot, initd, ws_zmink, ws_zmaxk,
                                                   ws_T, ws_den, ws_ee, N);

  stage2_kernel<<<NBATCH * KBS2, 256, 0, stream>>>(batch, xf, Wqg, Wkg1, Wkg2, Wvg1, Wvg2,
                                                   Wdot, Wv2, initd, ws_T, ws_den, ws_ee,
                                                   out_node, out_dummy, N);
}

// Round 3
// 79.397 us; speedup vs baseline: 1.4972x; 1.2304x over previous
//
#include <hip/hip_runtime.h>

#define NBATCH 32
#define DIST 5.0f
#define EPSV 1e-6f
#define INV_SQRT_F 0.17677669529663687f   // 1/sqrt(32)
#define SC_STAGE2 1.72633492e-4f          // 32^{-5/2}
#define KBS1 8    // slices per batch, stage-1 fused kernel -> 256 blocks
#define KBS2 16   // slices per batch, stage-2 kernel       -> 512 blocks

__device__ __forceinline__ float silu_f(float v) { return v / (1.0f + __expf(-v)); }

// monotonic float <-> uint mapping for atomic min/max on float values
__device__ __forceinline__ unsigned f2key(float f) {
  unsigned u = __float_as_uint(f);
  return (u & 0x80000000u) ? ~u : (u | 0x80000000u);
}
__device__ __forceinline__ float key2f(unsigned k) {
  return (k & 0x80000000u) ? __uint_as_float(k ^ 0x80000000u) : __uint_as_float(~k);
}

// ---------------- kernel A: z min/max + segment offsets + batch-independent tables ----------------
extern "C" __global__ __launch_bounds__(256)
void zseg_kernel(const float* __restrict__ pos, const int* __restrict__ batch,
                 unsigned* __restrict__ zminkey, unsigned* __restrict__ zmaxkey,
                 int* __restrict__ segoff,
                 const float* __restrict__ Wqd, const float* __restrict__ Wdot,
                 const float* __restrict__ Wqg, const float* __restrict__ Wk2,
                 const float* __restrict__ initd,
                 float* __restrict__ ws_Mk, float* __restrict__ ws_WQD,
                 int N, int ZB)
{
  const int tid = threadIdx.x;
  if ((int)blockIdx.x == ZB) {
    // batch-independent constants
    __shared__ float s_q[32], s_c[32];
    if (tid < 32) {
      float a = 0.f;
      #pragma unroll
      for (int f = 0; f < 32; f++) a += initd[f] * Wqd[f * 32 + tid];
      s_q[tid] = a * INV_SQRT_F;
    }
    __syncthreads();
    if (tid < 32) {
      float a = 0.f;
      #pragma unroll
      for (int f = 0; f < 32; f++) a += s_q[f] * Wdot[f * 32 + tid];
      s_c[tid] = a;
    }
    __syncthreads();
    {
      int f = tid >> 3, h = tid & 7;
      const float* w = &Wk2[h * 1024 + f * 32];
      float a = 0.f;
      #pragma unroll
      for (int g = 0; g < 32; g++) a += w[g] * s_c[g];
      ws_Mk[f * 8 + h] = a * (1.0f / 1024.0f);
    }
    for (int idx = tid; idx < 1024; idx += 256) {
      int f = idx >> 5, g = idx & 31;
      float a = 0.f;
      #pragma unroll
      for (int k = 0; k < 32; k++) a += Wqg[f * 32 + k] * Wdot[k * 32 + g];
      ws_WQD[idx] = a;
    }
    return;
  }
  __shared__ unsigned smin[NBATCH], smax[NBATCH];
  if (tid < NBATCH) { smin[tid] = 0xFFFFFFFFu; smax[tid] = 0u; }
  __syncthreads();
  int i = blockIdx.x * 256 + tid;
  if (i < N) {
    int b = batch[i];
    unsigned k = f2key(pos[3 * (size_t)i + 2]);
    atomicMin(&smin[b], k);
    atomicMax(&smax[b], k);
    int bprev = (i == 0) ? -1 : batch[i - 1];
    for (int bb = bprev + 1; bb <= b; bb++) segoff[bb] = i;
    if (i == N - 1) for (int bb = b + 1; bb <= NBATCH; bb++) segoff[bb] = N;
  }
  __syncthreads();
  if (tid < NBATCH) {
    if (smin[tid] != 0xFFFFFFFFu) atomicMin(&zminkey[tid], smin[tid]);
    if (smax[tid] != 0u)          atomicMax(&zmaxkey[tid], smax[tid]);
  }
}

// ---------------- kernel B: fused per-node stage-1 (ee, scores, exp, T, denom) ----------------
extern "C" __global__ __launch_bounds__(256)
void fused1_kernel(const float* __restrict__ pos,
                   const float* __restrict__ xfeat,
                   const float* __restrict__ bw,
                   const float* __restrict__ Wk1,
                   const float* __restrict__ Wv1,
                   const int*   __restrict__ segoff,
                   const unsigned* __restrict__ zminkey,
                   const unsigned* __restrict__ zmaxkey,
                   const float* __restrict__ ws_Mk,
                   float* __restrict__ Tacc,     // NB * 512
                   float* __restrict__ den,      // NB * 2
                   float* __restrict__ ws_ee,    // N * 16
                   int N)
{
  const int b   = blockIdx.x / KBS1;
  const int jb  = blockIdx.x % KBS1;
  const int tid = threadIdx.x;

  __shared__ float s_bw[8];
  __shared__ float s_Wk1[8][8], s_Wv1[8][8];
  __shared__ float s_Mk[32][8];          // [f][h], includes 1/1024
  __shared__ float s_exh[256][16];       // ex[s]*hv[s][h]
  __shared__ float s_xs[256][32];
  __shared__ float s_Tpart[4][512];
  __shared__ float s_red[256];

  if (tid < 8)  s_bw[tid] = bw[tid];
  if (tid < 64) { s_Wk1[tid >> 3][tid & 7] = Wk1[tid]; s_Wv1[tid >> 3][tid & 7] = Wv1[tid]; }
  s_Mk[tid >> 3][tid & 7] = ws_Mk[tid];
  const float zmin = key2f(zminkey[b]);
  const float zmax = key2f(zmaxkey[b]);
  const int s0 = segoff[b], s1 = segoff[b + 1];
  __syncthreads();

  const int cnt = s1 - s0;
  const int per = (cnt + KBS1 - 1) / KBS1;
  const int lo  = s0 + jb * per;
  const int hi  = min(lo + per, s1);

  float Treg[8] = {0,0,0,0,0,0,0,0};
  float d0 = 0.f, d1 = 0.f;
  const int group = tid >> 6;    // 0..3
  const int gt    = tid & 63;
  const int osh   = gt >> 2;     // 0..15 = s*8+h
  const int ofg   = gt & 3;      // f-block of 8

  for (int base = lo; base < hi; base += 256) {
    int i = base + tid;
    if (i < hi) {
      float z = pos[3 * (size_t)i + 2];
      float len0 = z - zmin + DIST;
      float len1 = zmax + DIST - z;
      float xv[32];
      const float4* xp = (const float4*)&xfeat[(size_t)i * 32];
      float4* xso = (float4*)s_xs[tid];
      #pragma unroll
      for (int q = 0; q < 8; q++) {
        float4 t = xp[q];
        xso[q] = t;
        xv[4*q] = t.x; xv[4*q+1] = t.y; xv[4*q+2] = t.z; xv[4*q+3] = t.w;
      }
      float u[8] = {0,0,0,0,0,0,0,0};
      #pragma unroll
      for (int f = 0; f < 32; f++) {
        float xf = xv[f];
        #pragma unroll
        for (int h = 0; h < 8; h++) u[h] += xf * s_Mk[f][h];
      }
      float4* eeo = (float4*)&ws_ee[(size_t)i * 16];
      #pragma unroll
      for (int s = 0; s < 2; s++) {
        float L = s ? len1 : len0;
        float inv = 1.0f / (L + EPSV);
        float ee[8];
        #pragma unroll
        for (int j = 0; j < 8; j++) ee[j] = __sinf(s_bw[j] * L) * inv;
        eeo[2*s]   = make_float4(ee[0], ee[1], ee[2], ee[3]);
        eeo[2*s+1] = make_float4(ee[4], ee[5], ee[6], ee[7]);
        float sc = 0.f;
        #pragma unroll
        for (int h = 0; h < 8; h++) {
          float a = 0.f;
          #pragma unroll
          for (int j = 0; j < 8; j++) a += ee[j] * s_Wk1[j][h];
          sc += silu_f(a) * u[h];
        }
        // softmax without max-subtraction (exact: ratio-invariant; clamp = overflow guard)
        float ex = __expf(fminf(fmaxf(sc, -60.f), 60.f));
        if (s) d1 += ex; else d0 += ex;
        #pragma unroll
        for (int h = 0; h < 8; h++) {
          float v = 0.f;
          #pragma unroll
          for (int j = 0; j < 8; j++) v += ee[j] * s_Wv1[j][h];
          s_exh[tid][8*s + h] = ex * silu_f(v);
        }
      }
    } else {
      #pragma unroll
      for (int h = 0; h < 16; h++) s_exh[tid][h] = 0.f;
      float4* xso = (float4*)s_xs[tid];
      #pragma unroll
      for (int q = 0; q < 8; q++) xso[q] = make_float4(0.f, 0.f, 0.f, 0.f);
    }
    __syncthreads();
    const int cbeg = group * 64;
    for (int c = cbeg; c < cbeg + 64; c++) {
      float eh = s_exh[c][osh];
      const float* xr = &s_xs[c][ofg * 8];
      #pragma unroll
      for (int k = 0; k < 8; k++) Treg[k] += eh * xr[k];
    }
    __syncthreads();
  }

  #pragma unroll
  for (int k = 0; k < 8; k++) s_Tpart[group][osh * 32 + ofg * 8 + k] = Treg[k];
  __syncthreads();
  for (int idx = tid; idx < 512; idx += 256) {
    float v = s_Tpart[0][idx] + s_Tpart[1][idx] + s_Tpart[2][idx] + s_Tpart[3][idx];
    atomicAdd(&Tacc[b * 512 + idx], v);
  }
  s_red[tid] = d0; __syncthreads();
  for (int off = 128; off > 0; off >>= 1) { if (tid < off) s_red[tid] += s_red[tid + off]; __syncthreads(); }
  if (tid == 0) atomicAdd(&den[b * 2 + 0], s_red[0]);
  __syncthreads();
  s_red[tid] = d1; __syncthreads();
  for (int off = 128; off > 0; off >>= 1) { if (tid < off) s_red[tid] += s_red[tid + off]; __syncthreads(); }
  if (tid == 0) atomicAdd(&den[b * 2 + 1], s_red[0]);
}

// ---------------- kernel C: per-batch stage-2 tables (dummy, Bvg, G) ----------------
extern "C" __global__ __launch_bounds__(256)
void prep2_kernel(const float* __restrict__ Wkg2, const float* __restrict__ Wvg2,
                  const float* __restrict__ Wv2,  const float* __restrict__ initd,
                  const float* __restrict__ Tacc, const float* __restrict__ den,
                  const float* __restrict__ ws_WQD,
                  float* __restrict__ out_dummy,  // NB*64
                  float* __restrict__ ws_Bvg,     // NB*512
                  float* __restrict__ ws_G)       // NB*512
{
  const int b   = blockIdx.x;
  const int tid = threadIdx.x;
  __shared__ float s_dummy[2][32];
  __shared__ float s_WQD[32][32];
  __shared__ float s_Bkg[16][32];

  if (tid < 64) {
    int s = tid >> 5, g = tid & 31;
    float acc = 0.f;
    #pragma unroll
    for (int h = 0; h < 8; h++) {
      const float* wv = &Wv2[h * 1024 + g];
      const float* Ts = &Tacc[b * 512 + (8 * s + h) * 32];
      #pragma unroll
      for (int f = 0; f < 32; f++) acc += Ts[f] * wv[f * 32];
    }
    float dn = den[b * 2 + s];
    float dv = initd[g] + (dn > 0.f ? acc * INV_SQRT_F / dn : 0.f);
    s_dummy[s][g] = dv;
    out_dummy[b * 64 + tid] = dv;
  }
  for (int idx = tid; idx < 1024; idx += 256) s_WQD[idx >> 5][idx & 31] = ws_WQD[idx];
  __syncthreads();
  for (int idx = tid; idx < 512; idx += 256) {
    int sh = idx >> 5, g = idx & 31;
    int s = sh >> 3, h = sh & 7;
    const float* wk = &Wkg2[h * 1024 + g];
    const float* wv = &Wvg2[h * 1024 + g];
    float a = 0.f, v = 0.f;
    #pragma unroll
    for (int f = 0; f < 32; f++) { float d = s_dummy[s][f]; a += d * wk[f * 32]; v += d * wv[f * 32]; }
    s_Bkg[sh][g] = a;
    ws_Bvg[b * 512 + idx] = v;
  }
  __syncthreads();
  for (int idx = tid; idx < 512; idx += 256) {
    int f = idx >> 4, sh = idx & 15;
    float a = 0.f;
    #pragma unroll
    for (int g = 0; g < 32; g++) a += s_WQD[f][g] * s_Bkg[sh][g];
    ws_G[b * 512 + idx] = a * SC_STAGE2;   // layout [f][sh]
  }
}

// ---------------- kernel D: stage-2 per-node ----------------
extern "C" __global__ __launch_bounds__(256)
void stage2_kernel(const float* __restrict__ xfeat,
                   const float* __restrict__ Wkg1,
                   const float* __restrict__ Wvg1,
                   const int*   __restrict__ segoff,
                   const float* __restrict__ ws_Bvg,
                   const float* __restrict__ ws_G,
                   const float* __restrict__ ws_ee,
                   float* __restrict__ out_node,
                   int N)
{
  const int b   = blockIdx.x / KBS2;
  const int jb  = blockIdx.x % KBS2;
  const int tid = threadIdx.x;

  __shared__ float s_Bvg[16][32];
  __shared__ float s_G[32][16];
  __shared__ float s_Wkg1[8][8], s_Wvg1[8][8];

  if (tid < 64) { s_Wkg1[tid >> 3][tid & 7] = Wkg1[tid]; s_Wvg1[tid >> 3][tid & 7] = Wvg1[tid]; }
  for (int idx = tid; idx < 512; idx += 256) {
    s_Bvg[idx >> 5][idx & 31] = ws_Bvg[b * 512 + idx];
    s_G[idx >> 4][idx & 15]   = ws_G[b * 512 + idx];
  }
  const int s0 = segoff[b], s1 = segoff[b + 1];
  __syncthreads();

  const int cnt = s1 - s0;
  const int per = (cnt + KBS2 - 1) / KBS2;
  const int lo = s0 + jb * per;
  const int hi = min(lo + per, s1);

  for (int i = lo + tid; i < hi; i += 256) {
    float ee[16];
    const float4* eei = (const float4*)&ws_ee[(size_t)i * 16];
    #pragma unroll
    for (int q = 0; q < 4; q++) { float4 t = eei[q]; ee[4*q] = t.x; ee[4*q+1] = t.y; ee[4*q+2] = t.z; ee[4*q+3] = t.w; }
    float hkg[16], hvg[16];
    #pragma unroll
    for (int s = 0; s < 2; s++) {
      #pragma unroll
      for (int h = 0; h < 8; h++) {
        float a = 0.f, v = 0.f;
        #pragma unroll
        for (int j = 0; j < 8; j++) { a += ee[8*s + j] * s_Wkg1[j][h]; v += ee[8*s + j] * s_Wvg1[j][h]; }
        hkg[8*s + h] = silu_f(a); hvg[8*s + h] = silu_f(v);
      }
    }
    float xv[32];
    const float4* xp = (const float4*)&xfeat[(size_t)i * 32];
    #pragma unroll
    for (int q = 0; q < 8; q++) { float4 t = xp[q]; xv[4*q] = t.x; xv[4*q+1] = t.y; xv[4*q+2] = t.z; xv[4*q+3] = t.w; }
    float ev[16] = {0,0,0,0,0,0,0,0,0,0,0,0,0,0,0,0};
    #pragma unroll
    for (int f = 0; f < 32; f++) {
      float xf = xv[f];
      #pragma unroll
      for (int sh = 0; sh < 16; sh++) ev[sh] += xf * s_G[f][sh];
    }
    float sc0 = 0.f, sc1 = 0.f;
    #pragma unroll
    for (int h = 0; h < 8; h++) { sc0 += hkg[h] * ev[h]; sc1 += hkg[8 + h] * ev[8 + h]; }
    float m = fmaxf(sc0, sc1);
    float a0 = __expf(sc0 - m), a1 = __expf(sc1 - m);
    float invd = 1.0f / (a0 + a1);
    float w0 = a0 * invd * INV_SQRT_F, w1 = a1 * invd * INV_SQRT_F;
    float ov[32];
    #pragma unroll
    for (int g = 0; g < 32; g++) ov[g] = xv[g];
    #pragma unroll
    for (int sh = 0; sh < 16; sh++) {
      float w = (sh < 8 ? w0 : w1) * hvg[sh];
      #pragma unroll
      for (int g = 0; g < 32; g++) ov[g] += w * s_Bvg[sh][g];
    }
    float4* op = (float4*)&out_node[(size_t)i * 32];
    #pragma unroll
    for (int q = 0; q < 8; q++) op[q] = make_float4(ov[4*q], ov[4*q+1], ov[4*q+2], ov[4*q+3]);
  }
}

extern "C" void kernel_launch(void* const* d_in, const int* in_sizes, int n_in,
                              void* d_out, int out_size, void* d_ws, size_t ws_size,
                              hipStream_t stream)
{
  const float* pos   = (const float*)d_in[0];
  const int*   batch = (const int*)d_in[1];
  const float* xf    = (const float*)d_in[2];
  const float* bw    = (const float*)d_in[3];
  const float* Wqd   = (const float*)d_in[4];
  const float* Wk1   = (const float*)d_in[5];
  const float* Wk2   = (const float*)d_in[6];
  const float* Wv1   = (const float*)d_in[7];
  const float* Wv2   = (const float*)d_in[8];
  const float* Wqg   = (const float*)d_in[9];
  const float* Wkg1  = (const float*)d_in[10];
  const float* Wkg2  = (const float*)d_in[11];
  const float* Wvg1  = (const float*)d_in[12];
  const float* Wvg2  = (const float*)d_in[13];
  const float* Wdot  = (const float*)d_in[14];
  const float* initd = (const float*)d_in[15];
  const int N = in_sizes[1];

  float* out       = (float*)d_out;
  float* out_node  = out;
  float* out_dummy = out + (size_t)N * 32;

  // workspace layout (float offsets)
  float*    ws        = (float*)d_ws;
  float*    ws_T      = ws;                           // [0, 16384)
  float*    ws_den    = ws + 16384;                   // [16384, 16448)
  unsigned* ws_zmaxk  = (unsigned*)(ws + 16448);      // 32 (init 0)
  unsigned* ws_zmink  = (unsigned*)(ws + 16480);      // 32 (init 0xFF)
  int*      ws_segoff = (int*)(ws + 16512);           // 33
  float*    ws_Mk     = ws + 16560;                   // 256
  float*    ws_WQD    = ws + 16816;                   // 1024
  float*    ws_Bvg    = ws + 17840;                   // 32*512
  float*    ws_G      = ws + 34224;                   // 32*512
  float*    ws_ee     = ws + 50608;                   // N*16

  hipMemsetAsync(ws_T, 0, (size_t)16480 * 4, stream);          // T, den, zmaxkey
  hipMemsetAsync(ws_zmink, 0xFF, (size_t)32 * 4, stream);      // zminkey

  const int ZB = (N + 255) / 256;
  zseg_kernel<<<ZB + 1, 256, 0, stream>>>(pos, batch, ws_zmink, ws_zmaxk, ws_segoff,
                                          Wqd, Wdot, Wqg, Wk2, initd, ws_Mk, ws_WQD, N, ZB);

  fused1_kernel<<<NBATCH * KBS1, 256, 0, stream>>>(pos, xf, bw, Wk1, Wv1, ws_segoff,
                                                   ws_zmink, ws_zmaxk, ws_Mk,
                                                   ws_T, ws_den, ws_ee, N);

  prep2_kernel<<<NBATCH, 256, 0, stream>>>(Wkg2, Wvg2, Wv2, initd, ws_T, ws_den,
                                           ws_WQD, out_dummy, ws_Bvg, ws_G);

  stage2_kernel<<<NBATCH * KBS2, 256, 0, stream>>>(xf, Wkg1, Wvg1, ws_segoff,
                                                   ws_Bvg, ws_G, ws_ee, out_node, N);
}